// Round 6
// baseline (375.558 us; speedup 1.0000x reference)
//
#include <hip/hip_runtime.h>

typedef _Float16 f16;
typedef __attribute__((ext_vector_type(8))) _Float16 f16x8;
typedef __attribute__((ext_vector_type(4))) _Float16 f16x4;
typedef __attribute__((ext_vector_type(4))) float    f32x4;

#define MFMA(a,b,c) __builtin_amdgcn_mfma_f32_16x16x32_f16(a,b,c,0,0,0)

constexpr int Hc = 8;

__device__ __forceinline__ f32x4 splat4(float v) { f32x4 r; r.x=v; r.y=v; r.z=v; r.w=v; return r; }
__device__ __forceinline__ f16x8 pack8(float4 a, float4 b) {
  f16x8 r = { (f16)a.x,(f16)a.y,(f16)a.z,(f16)a.w,(f16)b.x,(f16)b.y,(f16)b.z,(f16)b.w };
  return r;
}

typedef __attribute__((address_space(1))) void gvoid;
typedef __attribute__((address_space(3))) void lvoid;
__device__ __forceinline__ void dma16(const void* g, void* l) {
  __builtin_amdgcn_global_load_lds((gvoid*)g, (lvoid*)l, 16, 0, 0);
}

// ======================= PATH A (large workspace, DMA) =======================
// ws layout (bytes):
//   0         xh  f16[33554432]            x converted to f16, granule-swizzled q = p ^ (tok&7)
//   67108864  WC  f16[8][4][128][64]       per-(h,kb) LDS image; rows 0..63=Wfx, 64..127=Wx@Ws; q = p ^ (n&7)
//   67633152  bsp float[512]               bx@Ws + bsl
//   67635200  P   float[128][65536]        per-chunk partial slice_tokens
//   101189632 Pn  float[256][1024]         per-(chunk,wm) partial slice_norm
// NEED = 102238208

__global__ void prep_all(const float* __restrict__ x,   const float* __restrict__ Wx,
                         const float* __restrict__ Wfx, const float* __restrict__ Wsl,
                         const float* __restrict__ bx,  const float* __restrict__ bsl,
                         f16* __restrict__ xh, f16* __restrict__ WC, float* __restrict__ bsp) {
  __shared__ float tile[64][72];
  const int b = blockIdx.x, t = threadIdx.x;
  if (b < 1024) {                          // x convert + swizzle: 4096 granules/block
    #pragma unroll
    for (int it = 0; it < 16; ++it) {
      int G = b*4096 + it*256 + t;
      int tok = G >> 5, pos = G & 31;      // 32 granules per 256-f16 token row
      size_t base = (size_t)tok*256 + (pos >> 3)*64;
      int p = pos & 7;
      const float* src = x + base + p*8;
      float4 v0 = *(const float4*)src;
      float4 v1 = *(const float4*)(src + 4);
      *(f16x8*)&xh[base + ((p ^ (tok & 7))*8)] = pack8(v0, v1);
    }
  } else if (b < 1056) {                   // Wfx transpose -> WC rows 0..63 (swizzled image)
    const int bb = b - 1024;
    const int kb = bb & 3, c0 = (bb >> 2)*64, k0 = kb*64;
    const int r = t >> 4, c4 = (t & 15)*4;
    #pragma unroll
    for (int i = 0; i < 4; ++i) {
      float4 v = *(const float4*)&Wfx[(size_t)(k0 + r + i*16)*512 + c0 + c4];
      tile[r + i*16][c4] = v.x; tile[r + i*16][c4+1] = v.y;
      tile[r + i*16][c4+2] = v.z; tile[r + i*16][c4+3] = v.w;
    }
    __syncthreads();
    const int cl = t >> 2, kq = t & 3;
    const int col = c0 + cl, h = col >> 6, n = col & 63;
    f16 tmp[16];
    #pragma unroll
    for (int jj = 0; jj < 16; ++jj) tmp[jj] = (f16)tile[kq*16 + jj][cl];
    size_t rowbase = ((size_t)(h*4 + kb)*128 + n)*64;
    *(f16x8*)&WC[rowbase + ((2*kq    ) ^ (n & 7))*8] = *(f16x8*)&tmp[0];
    *(f16x8*)&WC[rowbase + ((2*kq + 1) ^ (n & 7))*8] = *(f16x8*)&tmp[8];
  } else if (b < 1120) {                   // Wxs = Wx_h @ Ws -> WC rows 64..127 (swizzled)
    const int bb = b - 1056;
    const int h = bb >> 3, k0 = (bb & 7)*32;
    const int k = t & 31, sq = t >> 5;
    float accs[8];
    #pragma unroll
    for (int jj = 0; jj < 8; ++jj) accs[jj] = 0.f;
    for (int d = 0; d < 64; ++d) {
      float a = Wx[(size_t)(k0 + k)*512 + h*64 + d];
      #pragma unroll
      for (int jj = 0; jj < 8; ++jj) accs[jj] += a * Wsl[d*64 + sq*8 + jj];
    }
    const int kb = k0 >> 6, kl = (k0 & 63) + k;
    const int p = kl >> 3, off = kl & 7;
    #pragma unroll
    for (int jj = 0; jj < 8; ++jj) {
      int n = 64 + sq*8 + jj;
      WC[((size_t)(h*4 + kb)*128 + n)*64 + (p ^ (n & 7))*8 + off] = (f16)accs[jj];
    }
  } else {                                 // bsp
    for (int u = t; u < 512; u += 256) {
      int h = u >> 6, s = u & 63;
      float a = bsl[s];
      for (int d = 0; d < 64; ++d) a += bx[h*64 + d] * Wsl[d*64 + s];
      bsp[h*64 + s] = a;
    }
  }
}

__global__ __launch_bounds__(256, 2)
void fused_a(const f16* __restrict__ xh, const float* __restrict__ bfx,
             const float* __restrict__ bsp, const float* __restrict__ temp,
             const f16* __restrict__ WC, float* __restrict__ P, float* __restrict__ Pn) {
  __shared__ alignas(16) f16 sm_x[8192];   // 16 KB: x tile [128t][64k swizzled] | alias fx^T [64d][128t swizzled]
  __shared__ alignas(16) f16 sm_w[8192];   // 16 KB: W tile [128n][64k swizzled] | alias w^T  [64s][128t swizzled]
  f16* fxT = sm_x;
  f16* wT  = sm_w;

  const int j    = blockIdx.x;
  const int xcd  = j & 7, slot = j >> 3;
  const int chunk = xcd*32 + (slot >> 3);
  const int h     = slot & 7;

  const int tid = threadIdx.x;
  const int wv = tid >> 6, lane = tid & 63, quad = lane >> 4, ln = lane & 15;
  const int wm = wv >> 1, wn = wv & 1;
  const int ci = wv >> 1, cj = wv & 1;
  const long tokBase = (long)chunk * 512;
  const int bIdx = (int)(tokBase >> 16);
  const int bh = bIdx*Hc + h;
  const int c  = chunk & 127;

  const float tc = fminf(fmaxf(temp[h], 0.5f), 5.0f);
  const float k2 = 1.44269504f / tc;

  float bv[4];
  { const float* bb = wn ? (bsp + h*64) : (bfx + h*64);
    #pragma unroll
    for (int nt = 0; nt < 4; ++nt) bv[nt] = bb[nt*16 + ln]; }

  f32x4 Tacc[2][2];
  #pragma unroll
  for (int i = 0; i < 2; ++i) { Tacc[i][0] = splat4(0.f); Tacc[i][1] = splat4(0.f); }
  float nacc[4] = {0.f, 0.f, 0.f, 0.f};

  const f16* WCh = WC + (size_t)h * 32768;
  const int lrow = lane >> 3, lcol = lane & 7;
  // per-lane DMA source bases (wave-uniform offsets added per (m0,kb,i))
  const f16* xlane = xh + (tokBase + lrow)*256 + lcol*8;
  const f16* wlane = WCh + lane*8;

  for (int m0 = 0; m0 < 4; ++m0) {
    f32x4 acc[4][4];
    #pragma unroll
    for (int mt = 0; mt < 4; ++mt)
      #pragma unroll
      for (int nt = 0; nt < 4; ++nt) acc[mt][nt] = splat4(bv[nt]);

    for (int kb = 0; kb < 4; ++kb) {
      __syncthreads();                     // prev tile reads (incl. phase C via aliases) done
      #pragma unroll
      for (int i = 0; i < 4; ++i) {
        int seg = 4*wv + i;                // 8 token/W rows per DMA
        dma16(xlane + (size_t)(m0*128 + seg*8)*256 + kb*64, &sm_x[seg*512]);
        dma16(wlane + (size_t)kb*8192 + seg*512,            &sm_w[seg*512]);
      }
      __syncthreads();                     // vmcnt(0) drain -> DMA complete for all waves
      #pragma unroll
      for (int ks = 0; ks < 2; ++ks) {
        const int qo = ((ks*4 + quad) ^ (ln & 7)) * 8;
        f16x8 af[4], bf[4];
        #pragma unroll
        for (int mt = 0; mt < 4; ++mt)
          af[mt] = *(const f16x8*)&sm_x[(wm*64 + mt*16 + ln)*64 + qo];
        #pragma unroll
        for (int nt = 0; nt < 4; ++nt)
          bf[nt] = *(const f16x8*)&sm_w[(wn*64 + nt*16 + ln)*64 + qo];
        #pragma unroll
        for (int mt = 0; mt < 4; ++mt)
          #pragma unroll
          for (int nt = 0; nt < 4; ++nt)
            acc[mt][nt] = MFMA(af[mt], bf[nt], acc[mt][nt]);
      }
    }
    __syncthreads();                       // phase-A reads done before alias rewrite

    // epilogue: granule p = wm*8 + mt*2 + (quad>>1); swizzle q = p ^ (row&15) = p ^ ln
    if (wn == 0) {
      #pragma unroll
      for (int mt = 0; mt < 4; ++mt) {
        const int p = wm*8 + mt*2 + (quad >> 1), ho = (quad & 1)*4;
        #pragma unroll
        for (int nt = 0; nt < 4; ++nt) {
          f16x4 v = { (f16)acc[mt][nt][0], (f16)acc[mt][nt][1],
                      (f16)acc[mt][nt][2], (f16)acc[mt][nt][3] };
          *(f16x4*)&fxT[(nt*16 + ln)*128 + (p ^ ln)*8 + ho] = v;
        }
      }
    } else {
      #pragma unroll
      for (int mt = 0; mt < 4; ++mt) {
        const int p = wm*8 + mt*2 + (quad >> 1), ho = (quad & 1)*4;
        float e[4][4], wout[4][4];
        #pragma unroll
        for (int nt = 0; nt < 4; ++nt)
          #pragma unroll
          for (int rg = 0; rg < 4; ++rg)
            e[nt][rg] = exp2f(acc[mt][nt][rg] * k2);     // logits bounded, no max-sub
        #pragma unroll
        for (int rg = 0; rg < 4; ++rg) {
          float rs = e[0][rg] + e[1][rg] + e[2][rg] + e[3][rg];
          #pragma unroll
          for (int dd = 1; dd < 16; dd <<= 1) rs += __shfl_xor(rs, dd, 64);
          float inv = 1.0f / rs;
          #pragma unroll
          for (int nt = 0; nt < 4; ++nt) {
            wout[nt][rg] = e[nt][rg] * inv;
            nacc[nt] += wout[nt][rg];
          }
        }
        #pragma unroll
        for (int nt = 0; nt < 4; ++nt) {
          f16x4 v = { (f16)wout[nt][0], (f16)wout[nt][1],
                      (f16)wout[nt][2], (f16)wout[nt][3] };
          *(f16x4*)&wT[(nt*16 + ln)*128 + (p ^ ln)*8 + ho] = v;
        }
      }
    }
    __syncthreads();

    // Phase C: T[s][d] += w^T @ fx, K=128 tokens
    #pragma unroll
    for (int ks = 0; ks < 4; ++ks) {
      const int q = (ks*4 + quad) ^ ln;
      f16x8 a0 = *(const f16x8*)&wT [(ci*32      + ln)*128 + q*8];
      f16x8 a1 = *(const f16x8*)&wT [(ci*32 + 16 + ln)*128 + q*8];
      f16x8 b0 = *(const f16x8*)&fxT[(cj*32      + ln)*128 + q*8];
      f16x8 b1 = *(const f16x8*)&fxT[(cj*32 + 16 + ln)*128 + q*8];
      Tacc[0][0] = MFMA(a0, b0, Tacc[0][0]);
      Tacc[0][1] = MFMA(a0, b1, Tacc[0][1]);
      Tacc[1][0] = MFMA(a1, b0, Tacc[1][0]);
      Tacc[1][1] = MFMA(a1, b1, Tacc[1][1]);
    }
  }

  // flush: plain partial writes (no atomics)
  float* Pb = P + (size_t)c*65536 + bh*4096;
  #pragma unroll
  for (int mt2 = 0; mt2 < 2; ++mt2)
    #pragma unroll
    for (int nt2 = 0; nt2 < 2; ++nt2)
      #pragma unroll
      for (int rg = 0; rg < 4; ++rg)
        Pb[(ci*32 + mt2*16 + quad*4 + rg)*64 + cj*32 + nt2*16 + ln] = Tacc[mt2][nt2][rg];
  if (wn == 1) {
    #pragma unroll
    for (int nt = 0; nt < 4; ++nt) {
      float v = nacc[nt];
      v += __shfl_xor(v, 16, 64);
      v += __shfl_xor(v, 32, 64);
      if (lane < 16) Pn[((size_t)c*2 + wm)*1024 + bh*64 + nt*16 + ln] = v;
    }
  }
}

__global__ void finalize_a(const float* __restrict__ P, const float* __restrict__ Pn,
                           float* __restrict__ out) {
  int i = blockIdx.x*256 + threadIdx.x;
  float s = 0.f;
  #pragma unroll 4
  for (int cc = 0; cc < 128; ++cc) s += P[(size_t)cc*65536 + i];
  int ns = i >> 6;
  float nv = 0.f;
  #pragma unroll 4
  for (int cc = 0; cc < 256; ++cc) nv += Pn[(size_t)cc*1024 + ns];
  out[i] = s / (nv + 0.01f);
}

// ======================= PATH B (fallback, round-5) =======================
constexpr int LDX = 72;
constexpr int LDT = 136;

__global__ void prep_b(const float* __restrict__ Wx, const float* __restrict__ Wfx,
                       const float* __restrict__ Wsl, const float* __restrict__ bx,
                       const float* __restrict__ bsl, f16* __restrict__ WC,
                       float* __restrict__ bsp) {
  __shared__ float tile[64][72];
  const int b = blockIdx.x, t = threadIdx.x;
  if (b < 32) {
    const int k0 = (b & 3)*64, c0 = (b >> 2)*64;
    const int r = t >> 4, c4 = (t & 15)*4;
    #pragma unroll
    for (int i = 0; i < 4; ++i) {
      float4 v = *(const float4*)&Wfx[(size_t)(k0 + r + i*16)*512 + c0 + c4];
      tile[r + i*16][c4] = v.x; tile[r + i*16][c4+1] = v.y;
      tile[r + i*16][c4+2] = v.z; tile[r + i*16][c4+3] = v.w;
    }
    __syncthreads();
    const int cl = t >> 2, kq = t & 3;
    const int col = c0 + cl, h = col >> 6, n = col & 63;
    f16 tmp[16];
    #pragma unroll
    for (int jj = 0; jj < 16; ++jj) tmp[jj] = (f16)tile[kq*16 + jj][cl];
    f16* dst = WC + (size_t)(h*128 + n)*256 + k0 + kq*16;
    *(f16x8*)dst       = *(f16x8*)&tmp[0];
    *(f16x8*)(dst + 8) = *(f16x8*)&tmp[8];
  } else if (b < 96) {
    const int bb = b - 32;
    const int h = bb >> 3, k0 = (bb & 7)*32;
    const int k = t & 31, sq = t >> 5;
    float accs[8];
    #pragma unroll
    for (int jj = 0; jj < 8; ++jj) accs[jj] = 0.f;
    for (int d = 0; d < 64; ++d) {
      float a = Wx[(size_t)(k0 + k)*512 + h*64 + d];
      #pragma unroll
      for (int jj = 0; jj < 8; ++jj) accs[jj] += a * Wsl[d*64 + sq*8 + jj];
    }
    #pragma unroll
    for (int jj = 0; jj < 8; ++jj)
      WC[(size_t)(h*128 + 64 + sq*8 + jj)*256 + k0 + k] = (f16)accs[jj];
  } else {
    for (int u = t; u < 512; u += 256) {
      int h = u >> 6, s = u & 63;
      float a = bsl[s];
      for (int d = 0; d < 64; ++d) a += bx[h*64 + d] * Wsl[d*64 + s];
      bsp[h*64 + s] = a;
    }
  }
}

__global__ __launch_bounds__(256, 2)
void fused_b(const float* __restrict__ x,   const float* __restrict__ bfx,
             const float* __restrict__ bsp, const float* __restrict__ temp,
             const f16* __restrict__ WC,    float* __restrict__ Tg,
             float* __restrict__ normg) {
  __shared__ alignas(16) char smem[2 * 128 * LDX * 2];
  f16* sm_x   = (f16*)smem;
  f16* sm_w   = (f16*)(smem + 128*LDX*2);
  f16* sm_fxT = sm_x;
  f16* sm_wT  = sm_w;

  const int j    = blockIdx.x;
  const int xcd  = j & 7, slot = j >> 3;
  const int chunk = xcd*32 + (slot >> 3);
  const int h     = slot & 7;

  const int tid = threadIdx.x;
  const int wv = tid >> 6, lane = tid & 63, quad = lane >> 4, ln = lane & 15;
  const int wm = wv >> 1, wn = wv & 1;
  const long tokBase = (long)chunk * 512;
  const int b  = (int)(tokBase >> 16);
  const int bh = b*Hc + h;

  const float tc = fminf(fmaxf(temp[h], 0.5f), 5.0f);
  const float k2 = 1.44269504f / tc;

  float bv[4];
  { const float* bb = (wn == 0) ? (bfx + h*64) : (bsp + h*64);
    #pragma unroll
    for (int nt = 0; nt < 4; ++nt) bv[nt] = bb[nt*16 + ln]; }

  f32x4 Tacc[2][2];
  #pragma unroll
  for (int i = 0; i < 2; ++i) { Tacc[i][0] = splat4(0.f); Tacc[i][1] = splat4(0.f); }
  float nacc[4] = {0.f, 0.f, 0.f, 0.f};
  const int ci = wv >> 1, cj = wv & 1;

  const f16* WCh = WC + (size_t)h * 128 * 256;
  const int r0 = tid >> 2, seg = tid & 3;
  const int wrow = tid >> 1, whalf = tid & 1;

  float4 xr[8]; f16x8 wr[4];
  auto loadx = [&](int m0, int kb) {
    const float* p = x + (tokBase + (long)m0*128 + r0)*256 + kb*64 + seg*16;
    xr[0] = *(const float4*)p;        xr[1] = *(const float4*)(p + 4);
    xr[2] = *(const float4*)(p + 8);  xr[3] = *(const float4*)(p + 12);
    p += 64 * 256;
    xr[4] = *(const float4*)p;        xr[5] = *(const float4*)(p + 4);
    xr[6] = *(const float4*)(p + 8);  xr[7] = *(const float4*)(p + 12);
  };
  auto loadw = [&](int kb) {
    const f16* p = WCh + wrow*256 + kb*64 + whalf*32;
    wr[0] = *(const f16x8*)p;         wr[1] = *(const f16x8*)(p + 8);
    wr[2] = *(const f16x8*)(p + 16);  wr[3] = *(const f16x8*)(p + 24);
  };

  loadx(0, 0); loadw(0);

  for (int m0 = 0; m0 < 4; ++m0) {
    f32x4 acc[4][4];
    #pragma unroll
    for (int mt = 0; mt < 4; ++mt)
      #pragma unroll
      for (int nt = 0; nt < 4; ++nt) acc[mt][nt] = splat4(bv[nt]);

    for (int kb = 0; kb < 4; ++kb) {
      __syncthreads();
      *(f16x8*)&sm_x[r0*LDX + seg*16]          = pack8(xr[0], xr[1]);
      *(f16x8*)&sm_x[r0*LDX + seg*16 + 8]      = pack8(xr[2], xr[3]);
      *(f16x8*)&sm_x[(r0+64)*LDX + seg*16]     = pack8(xr[4], xr[5]);
      *(f16x8*)&sm_x[(r0+64)*LDX + seg*16 + 8] = pack8(xr[6], xr[7]);
      *(f16x8*)&sm_w[wrow*LDX + whalf*32]      = wr[0];
      *(f16x8*)&sm_w[wrow*LDX + whalf*32 +  8] = wr[1];
      *(f16x8*)&sm_w[wrow*LDX + whalf*32 + 16] = wr[2];
      *(f16x8*)&sm_w[wrow*LDX + whalf*32 + 24] = wr[3];
      { int nkb = kb + 1, nm0 = m0;
        if (nkb == 4) { nkb = 0; ++nm0; }
        if (nm0 < 4) { loadx(nm0, nkb); loadw(nkb); } }
      __syncthreads();
      #pragma unroll
      for (int ks = 0; ks < 2; ++ks) {
        f16x8 af[4], bf[4];
        #pragma unroll
        for (int mt = 0; mt < 4; ++mt)
          af[mt] = *(const f16x8*)&sm_x[(wm*64 + mt*16 + ln)*LDX + ks*32 + quad*8];
        #pragma unroll
        for (int nt = 0; nt < 4; ++nt)
          bf[nt] = *(const f16x8*)&sm_w[(wn*64 + nt*16 + ln)*LDX + ks*32 + quad*8];
        #pragma unroll
        for (int mt = 0; mt < 4; ++mt)
          #pragma unroll
          for (int nt = 0; nt < 4; ++nt)
            acc[mt][nt] = MFMA(af[mt], bf[nt], acc[mt][nt]);
      }
    }
    __syncthreads();

    if (wn == 0) {
      #pragma unroll
      for (int mt = 0; mt < 4; ++mt)
        #pragma unroll
        for (int nt = 0; nt < 4; ++nt) {
          f16x4 v = { (f16)acc[mt][nt][0], (f16)acc[mt][nt][1],
                      (f16)acc[mt][nt][2], (f16)acc[mt][nt][3] };
          *(f16x4*)&sm_fxT[(nt*16 + ln)*LDT + wm*64 + mt*16 + quad*4] = v;
        }
    } else {
      #pragma unroll
      for (int mt = 0; mt < 4; ++mt) {
        float e[4][4], wout[4][4];
        #pragma unroll
        for (int nt = 0; nt < 4; ++nt)
          #pragma unroll
          for (int rg = 0; rg < 4; ++rg)
            e[nt][rg] = exp2f(acc[mt][nt][rg] * k2);
        #pragma unroll
        for (int rg = 0; rg < 4; ++rg) {
          float rs = e[0][rg] + e[1][rg] + e[2][rg] + e[3][rg];
          #pragma unroll
          for (int dd = 1; dd < 16; dd <<= 1) rs += __shfl_xor(rs, dd, 64);
          float inv = 1.0f / rs;
          #pragma unroll
          for (int nt = 0; nt < 4; ++nt) {
            wout[nt][rg] = e[nt][rg] * inv;
            nacc[nt] += wout[nt][rg];
          }
        }
        #pragma unroll
        for (int nt = 0; nt < 4; ++nt) {
          f16x4 v = { (f16)wout[nt][0], (f16)wout[nt][1],
                      (f16)wout[nt][2], (f16)wout[nt][3] };
          *(f16x4*)&sm_wT[(nt*16 + ln)*LDT + wm*64 + mt*16 + quad*4] = v;
        }
      }
    }
    __syncthreads();

    #pragma unroll
    for (int ks = 0; ks < 4; ++ks) {
      f16x8 a0 = *(const f16x8*)&sm_wT [(ci*32      + ln)*LDT + ks*32 + quad*8];
      f16x8 a1 = *(const f16x8*)&sm_wT [(ci*32 + 16 + ln)*LDT + ks*32 + quad*8];
      f16x8 b0 = *(const f16x8*)&sm_fxT[(cj*32      + ln)*LDT + ks*32 + quad*8];
      f16x8 b1 = *(const f16x8*)&sm_fxT[(cj*32 + 16 + ln)*LDT + ks*32 + quad*8];
      Tacc[0][0] = MFMA(a0, b0, Tacc[0][0]);
      Tacc[0][1] = MFMA(a0, b1, Tacc[0][1]);
      Tacc[1][0] = MFMA(a1, b0, Tacc[1][0]);
      Tacc[1][1] = MFMA(a1, b1, Tacc[1][1]);
    }
  }

  float* Tb = Tg + bh * 4096;
  #pragma unroll
  for (int mt2 = 0; mt2 < 2; ++mt2)
    #pragma unroll
    for (int nt2 = 0; nt2 < 2; ++nt2)
      #pragma unroll
      for (int rg = 0; rg < 4; ++rg) {
        int s = ci*32 + mt2*16 + quad*4 + rg;
        int d = cj*32 + nt2*16 + ln;
        atomicAdd(&Tb[s*64 + d], Tacc[mt2][nt2][rg]);
      }
  if (wn == 1) {
    #pragma unroll
    for (int nt = 0; nt < 4; ++nt) {
      float v = nacc[nt];
      v += __shfl_xor(v, 16, 64);
      v += __shfl_xor(v, 32, 64);
      if (lane < 16) atomicAdd(&normg[bh*64 + nt*16 + ln], v);
    }
  }
}

__global__ void finalize_b(const float* __restrict__ Tg, const float* __restrict__ normg,
                           float* __restrict__ out) {
  int i = blockIdx.x*256 + threadIdx.x;
  out[i] = Tg[i] / (normg[i >> 6] + 0.01f);
}

// ======================= launcher =======================
extern "C" void kernel_launch(void* const* d_in, const int* in_sizes, int n_in,
                              void* d_out, int out_size, void* d_ws, size_t ws_size,
                              hipStream_t stream) {
  const float* x    = (const float*)d_in[0];
  const float* Wx   = (const float*)d_in[1];
  const float* bx   = (const float*)d_in[2];
  const float* Wfx  = (const float*)d_in[3];
  const float* bfx  = (const float*)d_in[4];
  const float* Wsl  = (const float*)d_in[5];
  const float* bsl  = (const float*)d_in[6];
  const float* temp = (const float*)d_in[7];
  float* out = (float*)d_out;

  const size_t NEED = 102238208;           // xh + WC + bsp + P + Pn
  if (ws_size >= NEED) {
    f16*   xh  = (f16*)d_ws;
    f16*   WC  = (f16*)((char*)d_ws + 67108864);
    float* bsp = (float*)((char*)d_ws + 67633152);
    float* P   = (float*)((char*)d_ws + 67635200);
    float* Pn  = (float*)((char*)d_ws + 101189632);
    prep_all  <<<1121, 256, 0, stream>>>(x, Wx, Wfx, Wsl, bx, bsl, xh, WC, bsp);
    fused_a   <<<2048, 256, 0, stream>>>(xh, bfx, bsp, temp, WC, P, Pn);
    finalize_a<<<256, 256, 0, stream>>>(P, Pn, out);
  } else {
    float* Tg    = (float*)d_ws;
    float* normg = Tg + 16*4096;
    f16*   WC    = (f16*)((char*)d_ws + 266240);
    float* bsp   = (float*)((char*)d_ws + 790528);
    hipMemsetAsync(d_ws, 0, 266240, stream);
    prep_b    <<<97, 256, 0, stream>>>(Wx, Wfx, Wsl, bx, bsl, WC, bsp);
    fused_b   <<<2048, 256, 0, stream>>>(x, bfx, bsp, temp, WC, Tg, normg);
    finalize_b<<<256, 256, 0, stream>>>(Tg, normg, out);
  }
}